// Round 2
// baseline (2544.198 us; speedup 1.0000x reference)
//
#include <hip/hip_runtime.h>
#include <math.h>

__device__ __forceinline__ float gelu_f(float x){
    return 0.5f * x * (1.0f + erff(x * 0.70710678118654752f));
}

// EPI: 0:+bias  1:+bias,GELU  2:exp(acc-rowv[r])*scale  3:acc/(rowv[r]+1e-8)
//      4:+bias+resid[r*ldr+c] (resid may alias C)  5:atomicAdd into C
// AMODE: 0 row-major A[r*lda+k]; 1 concat(A,A2) each Acols wide; 2 transposed A[k*lda+r]
// BMODE: 0 row-major B[k*ldb+n]; 1 transposed B[n*ldb+k]
template<int AMODE,int BMODE,int EPI>
__global__ __launch_bounds__(256)
void gemm_f32(const float* __restrict__ A, const float* __restrict__ A2, int lda, int Acols,
              const float* __restrict__ Bp, int ldb,
              float* __restrict__ C, int ldc,
              const float* __restrict__ bias,
              const float* __restrict__ rowv,
              const float* __restrict__ resid, int ldr,
              int M, int N, int K, int splitK,
              long sA, long sB, long sC, long sRV, long sRes,
              float scale)
{
    const int bz = blockIdx.z;
    const int b  = bz / splitK, kc = bz % splitK;
    A += (long)b * sA;
    Bp += (long)b * sB;
    C  += (long)b * sC;
    const float* rv = rowv  ? rowv  + (long)b * sRV  : nullptr;
    const float* rs = resid ? resid + (long)b * sRes : nullptr;

    __shared__ float As[16][64];
    __shared__ float Bs[16][64];
    const int tid = threadIdx.x;
    const int tx = tid & 15, ty = tid >> 4;
    const int row0 = blockIdx.y * 64, col0 = blockIdx.x * 64;

    float acc[4][4] = {};

    const int kLen = K / splitK;
    const int kB = kc * kLen, kE = kB + kLen;

    for (int k0 = kB; k0 < kE; k0 += 16){
        if (AMODE == 2){
            const int dl = tid & 63, tl = tid >> 6;
            #pragma unroll
            for (int i = 0; i < 4; i++){
                const int t = k0 + tl + i*4;
                As[tl + i*4][dl] = A[(long)t * lda + row0 + dl];
            }
        } else {
            const int r = tid >> 2, kg = (tid & 3) * 4;
            const int gk = k0 + kg;
            float4 v4;
            if (AMODE == 1){
                v4 = (gk < Acols)
                   ? *(const float4*)&A [(long)(row0 + r) * Acols + gk]
                   : *(const float4*)&A2[(long)(row0 + r) * Acols + (gk - Acols)];
            } else {
                v4 = *(const float4*)&A[(long)(row0 + r) * lda + gk];
            }
            As[kg+0][r] = v4.x; As[kg+1][r] = v4.y;
            As[kg+2][r] = v4.z; As[kg+3][r] = v4.w;
        }
        if (BMODE == 0){
            const int kk = tid >> 4, ng = (tid & 15) * 4;
            *(float4*)&Bs[kk][ng] =
                *(const float4*)&Bp[(long)(k0 + kk) * ldb + col0 + ng];
        } else {
            const int n = tid >> 2, kg = (tid & 3) * 4;
            float4 v4 = *(const float4*)&Bp[(long)(col0 + n) * ldb + k0 + kg];
            Bs[kg+0][n] = v4.x; Bs[kg+1][n] = v4.y;
            Bs[kg+2][n] = v4.z; Bs[kg+3][n] = v4.w;
        }
        __syncthreads();
        #pragma unroll
        for (int kk = 0; kk < 16; kk++){
            float4 a4 = *(const float4*)&As[kk][ty*4];
            float4 b4 = *(const float4*)&Bs[kk][tx*4];
            float a[4]  = {a4.x, a4.y, a4.z, a4.w};
            float bb[4] = {b4.x, b4.y, b4.z, b4.w};
            #pragma unroll
            for (int i = 0; i < 4; i++)
                #pragma unroll
                for (int j = 0; j < 4; j++)
                    acc[i][j] = fmaf(a[i], bb[j], acc[i][j]);
        }
        __syncthreads();
    }

    #pragma unroll
    for (int i = 0; i < 4; i++){
        const int r = row0 + ty*4 + i;
        float rvv = 0.f;
        if (EPI == 2 || EPI == 3) rvv = rv[r];
        if (EPI == 5){
            #pragma unroll
            for (int j = 0; j < 4; j++)
                atomicAdd(&C[(long)r * ldc + col0 + tx*4 + j], acc[i][j]);
        } else {
            float vv[4];
            #pragma unroll
            for (int j = 0; j < 4; j++){
                const int c = col0 + tx*4 + j;
                float v = acc[i][j];
                if      (EPI == 0){ v += bias[c]; }
                else if (EPI == 1){ v += bias[c]; v = gelu_f(v); }
                else if (EPI == 2){ v = expf(v - rvv) * scale; }
                else if (EPI == 3){ v = v / (rvv + 1e-8f); }
                else if (EPI == 4){ v += bias[c] + rs[(long)r * ldr + c]; }
                vv[j] = v;
            }
            float4 o; o.x = vv[0]; o.y = vv[1]; o.z = vv[2]; o.w = vv[3];
            *(float4*)&C[(long)r * ldc + col0 + tx*4] = o;
        }
    }
}

// LayerNorm over D=384; one wave per row, 4 rows/block.
__global__ __launch_bounds__(256)
void ln_kernel(const float* __restrict__ x, float* __restrict__ o,
               const float* __restrict__ g, const float* __restrict__ bta)
{
    const int lane = threadIdx.x & 63;
    const long r = (long)blockIdx.x * 4 + (threadIdx.x >> 6);
    const float* xr = x + r * 384;
    float v[6]; float s = 0.f;
    #pragma unroll
    for (int i = 0; i < 6; i++){ v[i] = xr[lane + i*64]; s += v[i]; }
    #pragma unroll
    for (int off = 32; off; off >>= 1) s += __shfl_xor(s, off);
    const float mu = s * (1.0f/384.0f);
    float q = 0.f;
    #pragma unroll
    for (int i = 0; i < 6; i++){ float d = v[i] - mu; q += d*d; }
    #pragma unroll
    for (int off = 32; off; off >>= 1) q += __shfl_xor(q, off);
    const float inv = rsqrtf(q * (1.0f/384.0f) + 1e-5f);
    float* orow = o + r * 384;
    #pragma unroll
    for (int i = 0; i < 6; i++){
        const int c = lane + i*64;
        orow[c] = (v[i] - mu) * inv * g[c] + bta[c];
    }
}

// xd[r] = 0.5*||x_row||^2 over 384 cols (ld = 384)
__global__ __launch_bounds__(256)
void xd_kernel(const float* __restrict__ x, float* __restrict__ xd)
{
    const int lane = threadIdx.x & 63;
    const long r = (long)blockIdx.x * 4 + (threadIdx.x >> 6);
    const float* xr = x + r * 384;
    float s = 0.f;
    #pragma unroll
    for (int i = 0; i < 6; i++){ float a = xr[lane + i*64]; s += a*a; }
    #pragma unroll
    for (int off = 32; off; off >>= 1) s += __shfl_xor(s, off);
    if (lane == 0) xd[r] = 0.5f * s;
}

// Dn[r] = dot(qp[r,:192], kpsum[r/T,:192])   (r chunk-local)
__global__ __launch_bounds__(256)
void dn_kernel(const float* __restrict__ qp, const float* __restrict__ kpsum,
               float* __restrict__ Dn, int T)
{
    const int lane = threadIdx.x & 63;
    const long r = (long)blockIdx.x * 4 + (threadIdx.x >> 6);
    const int b = (int)(r / T);
    const float* qr = qp + r * 192;
    const float* ks = kpsum + (long)b * 192;
    float s = 0.f;
    #pragma unroll
    for (int i = 0; i < 3; i++){ const int m = lane + i*64; s += qr[m] * ks[m]; }
    #pragma unroll
    for (int off = 32; off; off >>= 1) s += __shfl_xor(s, off);
    if (lane == 0) Dn[r] = s;
}

// kpsum[b][m] += sum over a 448-row chunk of kp[b][t][m]
__global__ __launch_bounds__(192)
void kpsum_kernel(const float* __restrict__ kp, float* __restrict__ kpsum)
{
    const int b = blockIdx.x, ch = blockIdx.y, m = threadIdx.x;
    const float* base = kp + ((long)b * 3136 + (long)ch * 448) * 192 + m;
    float s = 0.f;
    for (int t = 0; t < 448; t++) s += base[(long)t * 192];
    atomicAdd(&kpsum[b * 192 + m], s);
}

__global__ __launch_bounds__(256)
void zero_kernel(float* __restrict__ p, long n)
{
    long i = (long)blockIdx.x * 256 + threadIdx.x;
    long stride = (long)gridDim.x * 256;
    for (; i < n; i += stride) p[i] = 0.f;
}

extern "C" void kernel_launch(void* const* d_in, const int* in_sizes, int n_in,
                              void* d_out, int out_size, void* d_ws, size_t ws_size,
                              hipStream_t stream)
{
    const int T = 3136;
    const float prm_scale = 0.07216878364870322f;  // 1/sqrt(192)

    const float* in1    = (const float*)d_in[0];
    const float* in2    = (const float*)d_in[1];
    const float* W1     = (const float*)d_in[2];
    const float* b1     = (const float*)d_in[3];
    const float* W2     = (const float*)d_in[4];
    const float* b2     = (const float*)d_in[5];
    const float* kqv_w  = (const float*)d_in[6];
    const float* kqv_b  = (const float*)d_in[7];
    const float* proj_w = (const float*)d_in[8];
    const float* proj_b = (const float*)d_in[9];
    const float* ln1_g  = (const float*)d_in[10];
    const float* ln1_b  = (const float*)d_in[11];
    const float* ln2_g  = (const float*)d_in[12];
    const float* ln2_b  = (const float*)d_in[13];
    const float* mlp_w1 = (const float*)d_in[14];
    const float* mlp_b1 = (const float*)d_in[15];
    const float* mlp_w2 = (const float*)d_in[16];
    const float* mlp_b2 = (const float*)d_in[17];
    const float* w_prm  = (const float*)d_in[18];
    float* out = (float*)d_out;

    // ---- choose chunk size (batches per pass) from ws_size ----
    // per-batch ws floats: T*(384+192+192+3) + 192 + 384*192 = 2,491,776 (~10 MB)
    const long perBatchF = (long)T * 771 + 192 + 384 * 192;
    int nb = 1;
    for (int cand = 16; cand >= 1; cand >>= 1){
        if ((long)cand * perBatchF * 4 <= (long)ws_size){ nb = cand; break; }
    }

    const dim3 blk(256);

    for (int b0 = 0; b0 < 16; b0 += nb){
        const int Mc = nb * T;               // rows this chunk
        const int gy = Mc / 64;              // 64-row tiles
        const float* i1 = in1 + (long)b0 * T * 384;
        const float* i2 = in2 + (long)b0 * T * 384;
        float* outc = out + (long)b0 * T * 384;

        float* wa    = (float*)d_ws;          // Mc*384
        float* kp    = wa    + (long)Mc * 384; // Mc*192
        float* qp    = kp    + (long)Mc * 192; // Mc*192  (kp..qp = contiguous Mc*384)
        float* xdv   = qp    + (long)Mc * 192; // Mc
        float* Dn    = xdv   + Mc;             // Mc
        float* kpsum = Dn    + Mc;             // nb*192
        float* kptv  = kpsum + (long)nb * 192; // nb*384*192

        // 1) wa = GELU([i1|i2] @ W1 + b1)
        gemm_f32<1,0,1><<<dim3(6,gy,1), blk, 0, stream>>>(
            i1, i2, 384, 384, W1, 384, wa, 384, b1, nullptr, nullptr, 0,
            Mc, 384, 768, 1, 0,0,0,0,0, 0.f);
        // 2) x = wa @ W2 + b2 -> outc
        gemm_f32<0,0,0><<<dim3(6,gy,1), blk, 0, stream>>>(
            wa, nullptr, 384, 0, W2, 384, outc, 384, b2, nullptr, nullptr, 0,
            Mc, 384, 384, 1, 0,0,0,0,0, 0.f);
        // 3) xn = LN1(x) -> wa
        ln_kernel<<<dim3(Mc/4), blk, 0, stream>>>(outc, wa, ln1_g, ln1_b);
        // 4) k = xn @ kqv_w[:,0:384] + kqv_b[0:384] -> outc
        gemm_f32<0,0,0><<<dim3(6,gy,1), blk, 0, stream>>>(
            wa, nullptr, 384, 0, kqv_w, 1152, outc, 384, kqv_b, nullptr, nullptr, 0,
            Mc, 384, 384, 1, 0,0,0,0,0, 0.f);
        // 5) xd_k ; kp = exp(k @ w_prm^T - xd_k)*scale
        xd_kernel<<<dim3(Mc/4), blk, 0, stream>>>(outc, xdv);
        gemm_f32<0,1,2><<<dim3(3,gy,1), blk, 0, stream>>>(
            outc, nullptr, 384, 0, w_prm, 384, kp, 192, nullptr, xdv, nullptr, 0,
            Mc, 192, 384, 1, 0,0,0,0,0, prm_scale);
        // 6) q -> outc ; xd_q ; qp
        gemm_f32<0,0,0><<<dim3(6,gy,1), blk, 0, stream>>>(
            wa, nullptr, 384, 0, kqv_w + 384, 1152, outc, 384, kqv_b + 384, nullptr, nullptr, 0,
            Mc, 384, 384, 1, 0,0,0,0,0, 0.f);
        xd_kernel<<<dim3(Mc/4), blk, 0, stream>>>(outc, xdv);
        gemm_f32<0,1,2><<<dim3(3,gy,1), blk, 0, stream>>>(
            outc, nullptr, 384, 0, w_prm, 384, qp, 192, nullptr, xdv, nullptr, 0,
            Mc, 192, 384, 1, 0,0,0,0,0, prm_scale);
        // 7) v -> outc
        gemm_f32<0,0,0><<<dim3(6,gy,1), blk, 0, stream>>>(
            wa, nullptr, 384, 0, kqv_w + 768, 1152, outc, 384, kqv_b + 768, nullptr, nullptr, 0,
            Mc, 384, 384, 1, 0,0,0,0,0, 0.f);
        // 8) zero accumulators; kpsum; kptv[b] = v[b]^T @ kp[b] (split-K=7, atomic)
        {
            long nz = (long)nb * 192 + (long)nb * 384 * 192;
            zero_kernel<<<dim3(512), blk, 0, stream>>>(kpsum, nz);
        }
        kpsum_kernel<<<dim3(nb,7,1), dim3(192), 0, stream>>>(kp, kpsum);
        gemm_f32<2,0,5><<<dim3(3,6,nb*7), blk, 0, stream>>>(
            outc, nullptr, 384, 0, kp, 192, kptv, 192, nullptr, nullptr, nullptr, 0,
            384, 192, 3136, 7, (long)T*384, (long)T*192, (long)384*192, 0, 0, 0.f);
        // 9) Dn
        dn_kernel<<<dim3(Mc/4), blk, 0, stream>>>(qp, kpsum, Dn, T);
        // 10) t_att[b] = (qp[b] @ kptv[b]^T) / (Dn + 1e-8) -> wa
        gemm_f32<0,1,3><<<dim3(6,49,nb), blk, 0, stream>>>(
            qp, nullptr, 192, 0, kptv, 192, wa, 384, nullptr, Dn, nullptr, 0,
            3136, 384, 192, 1, (long)T*192, (long)384*192, (long)T*384, (long)T, 0, 0.f);
        // 11) y = t_att @ proj_w + proj_b + v  (in-place residual on outc)
        gemm_f32<0,0,4><<<dim3(6,gy,1), blk, 0, stream>>>(
            wa, nullptr, 384, 0, proj_w, 384, outc, 384, proj_b, nullptr, outc, 384,
            Mc, 384, 384, 1, 0,0,0,0,0, 0.f);
        // 12) z = LN2(y) -> wa
        ln_kernel<<<dim3(Mc/4), blk, 0, stream>>>(outc, wa, ln2_g, ln2_b);
        // 13) h = GELU(z @ mlp_w1 + mlp_b1) -> kp region (Mc*384 contiguous)
        gemm_f32<0,0,1><<<dim3(6,gy,1), blk, 0, stream>>>(
            wa, nullptr, 384, 0, mlp_w1, 384, kp, 384, mlp_b1, nullptr, nullptr, 0,
            Mc, 384, 384, 1, 0,0,0,0,0, 0.f);
        // 14) out = h @ mlp_w2 + mlp_b2 + y  (in-place residual on outc)
        gemm_f32<0,0,4><<<dim3(6,gy,1), blk, 0, stream>>>(
            kp, nullptr, 384, 0, mlp_w2, 384, outc, 384, mlp_b2, nullptr, outc, 384,
            Mc, 384, 384, 1, 0,0,0,0,0, 0.f);
    }
}

// Round 3
// 1511.801 us; speedup vs baseline: 1.6829x; 1.6829x over previous
//
#include <hip/hip_runtime.h>
#include <math.h>

typedef unsigned short u16;
typedef unsigned int   u32;
typedef __attribute__((ext_vector_type(8))) short short8;
typedef __attribute__((ext_vector_type(4))) float f32x4;
typedef __attribute__((ext_vector_type(4))) u32   u32x4;

__device__ __forceinline__ float gelu_f(float x){
    return 0.5f * x * (1.0f + erff(x * 0.70710678118654752f));
}
__device__ __forceinline__ u16 f2b(float x){
    union{float f; u32 u;} v; v.f = x;
    u32 r = (v.u + 0x7fffu + ((v.u >> 16) & 1u)) >> 16;
    return (u16)r;
}
__device__ __forceinline__ float b2f(u16 h){
    union{u32 u; float f;} v; v.u = ((u32)h) << 16; return v.f;
}

// ===================== bf16 MFMA GEMM =====================
// A: bf16 [M][lda] row-major (k contiguous). B: bf16 [N][ldb] row-major (k contiguous).
// Tile 128x128, BK=32, 256 threads = 4 waves, each wave 64x64 (4x4 frags of 16x16).
// EPI: 0:+bias->bf16  1:+bias,GELU->bf16  2:+bias->f32  3:/(rowv[r]+1e-8)->bf16  4:+bias+resid->f32
template<int EPI, int GUARD>
__global__ __launch_bounds__(256)
void gemm_bf16(const u16* __restrict__ A, int lda,
               const u16* __restrict__ B, int ldb,
               void* __restrict__ Cv, int ldc,
               const float* __restrict__ bias,
               const float* __restrict__ rowv,
               const float* __restrict__ resid,
               int Mrows, int K,
               long sA, long sB, long sC, long sRV)
{
    const int bz = blockIdx.z;
    A += bz * sA;  B += bz * sB;
    const float* rv = (EPI == 3) ? rowv + bz * sRV : nullptr;

    __shared__ u16 As[4096];   // [kb][m][8]
    __shared__ u16 Bs[4096];   // [kb][n][8]

    const int tid = threadIdx.x;
    const int row0 = blockIdx.y * 128, col0 = blockIdx.x * 128;

    f32x4 acc[4][4] = {};

    const int l  = tid & 63, w = tid >> 6;
    const int wr = w >> 1,  wc = w & 1;
    const int g  = l >> 4,  mr = l & 15;

    // staging: thread t covers chunks 2t, 2t+1 ; chunk c: kb=c&3, m=c>>2
    const int cm = tid >> 1;          // row/col within tile
    const int ck = (tid & 1) * 2;     // kb base (0 or 2)

    for (int k0 = 0; k0 < K; k0 += 32){
        const u16* ga = A + (long)(row0 + cm) * lda + k0 + ck * 8;
        const u16* gb = B + (long)(col0 + cm) * ldb + k0 + ck * 8;
        u32x4 ra0 = *(const u32x4*)ga;
        u32x4 ra1 = *(const u32x4*)(ga + 8);
        u32x4 rb0 = *(const u32x4*)gb;
        u32x4 rb1 = *(const u32x4*)(gb + 8);
        __syncthreads();
        *(u32x4*)&As[((ck + 0) * 128 + cm) * 8] = ra0;
        *(u32x4*)&As[((ck + 1) * 128 + cm) * 8] = ra1;
        *(u32x4*)&Bs[((ck + 0) * 128 + cm) * 8] = rb0;
        *(u32x4*)&Bs[((ck + 1) * 128 + cm) * 8] = rb1;
        __syncthreads();

        short8 af[4], bfr[4];
        #pragma unroll
        for (int i = 0; i < 4; i++)
            af[i] = *(const short8*)&As[(g * 128 + wr * 64 + i * 16 + mr) * 8];
        #pragma unroll
        for (int j = 0; j < 4; j++)
            bfr[j] = *(const short8*)&Bs[(g * 128 + wc * 64 + j * 16 + mr) * 8];
        #pragma unroll
        for (int i = 0; i < 4; i++)
            #pragma unroll
            for (int j = 0; j < 4; j++)
                acc[i][j] = __builtin_amdgcn_mfma_f32_16x16x32_bf16(af[i], bfr[j], acc[i][j], 0, 0, 0);
    }

    float* Cf = (float*)Cv + bz * sC;
    u16*   Cb = (u16*)Cv   + bz * sC;

    #pragma unroll
    for (int i = 0; i < 4; i++){
        #pragma unroll
        for (int j = 0; j < 4; j++){
            const int col = col0 + wc * 64 + j * 16 + mr;
            float bv = 0.f;
            if (EPI == 0 || EPI == 1 || EPI == 2 || EPI == 4) bv = bias[col];
            #pragma unroll
            for (int r = 0; r < 4; r++){
                const int row = row0 + wr * 64 + i * 16 + g * 4 + r;
                if (GUARD && row >= Mrows) continue;
                float vv = acc[i][j][r];
                if      (EPI == 1){ vv += bv; vv = gelu_f(vv); }
                else if (EPI == 3){ vv = vv / (rv[row] + 1e-8f); }
                else if (EPI == 4){ vv += bv + resid[(long)row * ldc + col]; }
                else              { vv += bv; }
                if (EPI == 2 || EPI == 4) Cf[(long)row * ldc + col] = vv;
                else                       Cb[(long)row * ldc + col] = f2b(vv);
            }
        }
    }
}

// ===================== fp32 SIMT GEMM (exponent-sensitive path) =====================
// EPI: 0:+bias  2:exp(acc-rowv[r])*scale  5:atomicAdd
// AMODE: 0 row-major A[r*lda+k]; 2 transposed A[k*lda+r]
// BMODE: 0 row-major B[k*ldb+n]; 1 transposed B[n*ldb+k]
// OUTBF: EPI2 output as bf16
template<int AMODE,int BMODE,int EPI,int OUTBF>
__global__ __launch_bounds__(256)
void gemm_f32(const float* __restrict__ A, int lda,
              const float* __restrict__ Bp, int ldb,
              float* __restrict__ C, int ldc,
              const float* __restrict__ bias,
              const float* __restrict__ rowv,
              int M, int N, int K, int splitK,
              long sA, long sB, long sC, long sRV,
              float scale)
{
    const int bz = blockIdx.z;
    const int b  = bz / splitK, kc = bz % splitK;
    A += (long)b * sA;
    Bp += (long)b * sB;
    C  += (long)b * sC;
    const float* rv = rowv ? rowv + (long)b * sRV : nullptr;

    __shared__ float As[16][64];
    __shared__ float Bs[16][64];
    const int tid = threadIdx.x;
    const int tx = tid & 15, ty = tid >> 4;
    const int row0 = blockIdx.y * 64, col0 = blockIdx.x * 64;

    float acc[4][4] = {};

    const int kLen = K / splitK;
    const int kB = kc * kLen, kE = kB + kLen;

    for (int k0 = kB; k0 < kE; k0 += 16){
        if (AMODE == 2){
            const int dl = tid & 63, tl = tid >> 6;
            #pragma unroll
            for (int i = 0; i < 4; i++){
                const int t = k0 + tl + i*4;
                As[tl + i*4][dl] = A[(long)t * lda + row0 + dl];
            }
        } else {
            const int r = tid >> 2, kg = (tid & 3) * 4;
            float4 v4 = *(const float4*)&A[(long)(row0 + r) * lda + k0 + kg];
            As[kg+0][r] = v4.x; As[kg+1][r] = v4.y;
            As[kg+2][r] = v4.z; As[kg+3][r] = v4.w;
        }
        if (BMODE == 0){
            const int kk = tid >> 4, ng = (tid & 15) * 4;
            *(float4*)&Bs[kk][ng] =
                *(const float4*)&Bp[(long)(k0 + kk) * ldb + col0 + ng];
        } else {
            const int n = tid >> 2, kg = (tid & 3) * 4;
            float4 v4 = *(const float4*)&Bp[(long)(col0 + n) * ldb + k0 + kg];
            Bs[kg+0][n] = v4.x; Bs[kg+1][n] = v4.y;
            Bs[kg+2][n] = v4.z; Bs[kg+3][n] = v4.w;
        }
        __syncthreads();
        #pragma unroll
        for (int kk = 0; kk < 16; kk++){
            float4 a4 = *(const float4*)&As[kk][ty*4];
            float4 b4 = *(const float4*)&Bs[kk][tx*4];
            float a[4]  = {a4.x, a4.y, a4.z, a4.w};
            float bb[4] = {b4.x, b4.y, b4.z, b4.w};
            #pragma unroll
            for (int i = 0; i < 4; i++)
                #pragma unroll
                for (int j = 0; j < 4; j++)
                    acc[i][j] = fmaf(a[i], bb[j], acc[i][j]);
        }
        __syncthreads();
    }

    #pragma unroll
    for (int i = 0; i < 4; i++){
        const int r = row0 + ty*4 + i;
        float rvv = 0.f;
        if (EPI == 2) rvv = rv[r];
        if (EPI == 5){
            #pragma unroll
            for (int j = 0; j < 4; j++)
                atomicAdd(&C[(long)r * ldc + col0 + tx*4 + j], acc[i][j]);
        } else {
            float vv[4];
            #pragma unroll
            for (int j = 0; j < 4; j++){
                const int c = col0 + tx*4 + j;
                float v = acc[i][j];
                if      (EPI == 0){ v += bias[c]; }
                else if (EPI == 2){ v = expf(v - rvv) * scale; }
                vv[j] = v;
            }
            if (EPI == 2 && OUTBF){
                u16* Cb = (u16*)C;
                #pragma unroll
                for (int j = 0; j < 4; j++)
                    Cb[(long)r * ldc + col0 + tx*4 + j] = f2b(vv[j]);
            } else {
                float4 o; o.x = vv[0]; o.y = vv[1]; o.z = vv[2]; o.w = vv[3];
                *(float4*)&C[(long)r * ldc + col0 + tx*4] = o;
            }
        }
    }
}

// LayerNorm over D=384 (f32 in); optional f32 and bf16 outputs.
__global__ __launch_bounds__(256)
void ln_kernel(const float* __restrict__ x, float* __restrict__ of, u16* __restrict__ ob,
               const float* __restrict__ g, const float* __restrict__ bta)
{
    const int lane = threadIdx.x & 63;
    const long r = (long)blockIdx.x * 4 + (threadIdx.x >> 6);
    const float* xr = x + r * 384;
    float v[6]; float s = 0.f;
    #pragma unroll
    for (int i = 0; i < 6; i++){ v[i] = xr[lane + i*64]; s += v[i]; }
    #pragma unroll
    for (int off = 32; off; off >>= 1) s += __shfl_xor(s, off);
    const float mu = s * (1.0f/384.0f);
    float q = 0.f;
    #pragma unroll
    for (int i = 0; i < 6; i++){ float d = v[i] - mu; q += d*d; }
    #pragma unroll
    for (int off = 32; off; off >>= 1) q += __shfl_xor(q, off);
    const float inv = rsqrtf(q * (1.0f/384.0f) + 1e-5f);
    #pragma unroll
    for (int i = 0; i < 6; i++){
        const int c = lane + i*64;
        const float val = (v[i] - mu) * inv * g[c] + bta[c];
        if (of) of[r * 384 + c] = val;
        if (ob) ob[r * 384 + c] = f2b(val);
    }
}

__global__ __launch_bounds__(256)
void xd_kernel(const float* __restrict__ x, float* __restrict__ xd)
{
    const int lane = threadIdx.x & 63;
    const long r = (long)blockIdx.x * 4 + (threadIdx.x >> 6);
    const float* xr = x + r * 384;
    float s = 0.f;
    #pragma unroll
    for (int i = 0; i < 6; i++){ float a = xr[lane + i*64]; s += a*a; }
    #pragma unroll
    for (int off = 32; off; off >>= 1) s += __shfl_xor(s, off);
    if (lane == 0) xd[r] = 0.5f * s;
}

// Dn[r] = dot(qp_bf16[r,:192], kpsum[r/T,:192])
__global__ __launch_bounds__(256)
void dn_kernel(const u16* __restrict__ qp, const float* __restrict__ kpsum,
               float* __restrict__ Dn, int T)
{
    const int lane = threadIdx.x & 63;
    const long r = (long)blockIdx.x * 4 + (threadIdx.x >> 6);
    const int b = (int)(r / T);
    const u16* qr = qp + r * 192;
    const float* ks = kpsum + (long)b * 192;
    float s = 0.f;
    #pragma unroll
    for (int i = 0; i < 3; i++){ const int m = lane + i*64; s += b2f(qr[m]) * ks[m]; }
    #pragma unroll
    for (int off = 32; off; off >>= 1) s += __shfl_xor(s, off);
    if (lane == 0) Dn[r] = s;
}

__global__ __launch_bounds__(192)
void kpsum_kernel(const float* __restrict__ kp, float* __restrict__ kpsum)
{
    const int b = blockIdx.x, ch = blockIdx.y, m = threadIdx.x;
    const float* base = kp + ((long)b * 3136 + (long)ch * 448) * 192 + m;
    float s = 0.f;
    for (int t = 0; t < 448; t++) s += base[(long)t * 192];
    atomicAdd(&kpsum[b * 192 + m], s);
}

__global__ __launch_bounds__(256)
void zero_kernel(float* __restrict__ p, long n)
{
    long i = (long)blockIdx.x * 256 + threadIdx.x;
    long stride = (long)gridDim.x * 256;
    for (; i < n; i += stride) p[i] = 0.f;
}

// concat(in1,in2) row-major -> bf16 [Mc][768]; one thread per 4 elems
__global__ __launch_bounds__(256)
void ca_kernel(const float* __restrict__ i1, const float* __restrict__ i2,
               u16* __restrict__ a0, long nquad)
{
    long idx = (long)blockIdx.x * 256 + threadIdx.x;
    if (idx >= nquad) return;
    const long r = idx / 192;
    const int  c0 = (int)(idx % 192) * 4;
    const float* src = (c0 < 384) ? &i1[r * 384 + c0] : &i2[r * 384 + (c0 - 384)];
    float4 v = *(const float4*)src;
    u32 w0 = (u32)f2b(v.x) | ((u32)f2b(v.y) << 16);
    u32 w1 = (u32)f2b(v.z) | ((u32)f2b(v.w) << 16);
    *(uint2*)&a0[r * 768 + c0] = make_uint2(w0, w1);
}

// wt[n*K + k] = bf16(w[k*N + n])
__global__ __launch_bounds__(256)
void wt_kernel(const float* __restrict__ w, u16* __restrict__ wt, int K, int N, long total)
{
    long idx = (long)blockIdx.x * 256 + threadIdx.x;
    if (idx >= total) return;
    const long n = idx / K, k = idx - n * K;
    wt[idx] = f2b(w[k * N + n]);
}

// flat f32 -> bf16
__global__ __launch_bounds__(256)
void cvt_kernel(const float* __restrict__ s, u16* __restrict__ d, long n4)
{
    long idx = (long)blockIdx.x * 256 + threadIdx.x;
    if (idx >= n4) return;
    float4 v = *(const float4*)&s[idx * 4];
    u32 w0 = (u32)f2b(v.x) | ((u32)f2b(v.y) << 16);
    u32 w1 = (u32)f2b(v.z) | ((u32)f2b(v.w) << 16);
    *(uint2*)&d[idx * 4] = make_uint2(w0, w1);
}

extern "C" void kernel_launch(void* const* d_in, const int* in_sizes, int n_in,
                              void* d_out, int out_size, void* d_ws, size_t ws_size,
                              hipStream_t stream)
{
    const long T = 3136;
    const float prm_scale = 0.07216878364870322f;  // 1/sqrt(192)

    const float* in1    = (const float*)d_in[0];
    const float* in2    = (const float*)d_in[1];
    const float* W1     = (const float*)d_in[2];
    const float* b1     = (const float*)d_in[3];
    const float* W2     = (const float*)d_in[4];
    const float* b2     = (const float*)d_in[5];
    const float* kqv_w  = (const float*)d_in[6];
    const float* kqv_b  = (const float*)d_in[7];
    const float* proj_w = (const float*)d_in[8];
    const float* proj_b = (const float*)d_in[9];
    const float* ln1_g  = (const float*)d_in[10];
    const float* ln1_b  = (const float*)d_in[11];
    const float* ln2_g  = (const float*)d_in[12];
    const float* ln2_b  = (const float*)d_in[13];
    const float* mlp_w1 = (const float*)d_in[14];
    const float* mlp_b1 = (const float*)d_in[15];
    const float* mlp_w2 = (const float*)d_in[16];
    const float* mlp_b2 = (const float*)d_in[17];
    const float* w_prm  = (const float*)d_in[18];
    float* out = (float*)d_out;

    // ---- workspace layout ----
    char* p = (char*)d_ws;
    auto alloc = [&](long bytes)->char*{ char* r = p; p += (bytes + 255) & ~255L; return r; };

    // chunk-invariant: transposed bf16 weights
    u16* w1t  = (u16*)alloc(294912L * 2);   // [384][768]
    u16* w2t  = (u16*)alloc(147456L * 2);   // [384][384]
    u16* kqvt = (u16*)alloc(442368L * 2);   // [1152][384]
    u16* prjt = (u16*)alloc(147456L * 2);
    u16* m1t  = (u16*)alloc(147456L * 2);
    u16* m2t  = (u16*)alloc(147456L * 2);
    char* chunkBase = p;

    // pick nb (batches per chunk): per-batch footprint ~33 MB
    const long perBatch =
        1728L * T * 2 +            // bf16 activations: a0 768 + h1 384 + xn 384 + qp 192
        1730L * T * 4 +            // f32: x,xn,kscr,v (4*384) + kp 192 + xd,Dn
        (192L + 73728L) * 4 +      // kpsum + kptv f32
        73728L * 2;                // kptv bf16
    const long fixed = (long)(chunkBase - (char*)d_ws) + 64L * 192 * 4 + (1L << 20);
    int nb = 2;
    for (int cand = 16; cand >= 2; cand >>= 1){
        if (fixed + (long)cand * perBatch + 32L * 256 <= (long)ws_size){ nb = cand; break; }
    }

    const dim3 blk(256);

    // weight transpose+convert (once per call; idempotent)
    wt_kernel<<<dim3((294912 + 255) / 256), blk, 0, stream>>>(W1, w1t, 768, 384, 294912);
    wt_kernel<<<dim3((147456 + 255) / 256), blk, 0, stream>>>(W2, w2t, 384, 384, 147456);
    wt_kernel<<<dim3((442368 + 255) / 256), blk, 0, stream>>>(kqv_w, kqvt, 384, 1152, 442368);
    wt_kernel<<<dim3((147456 + 255) / 256), blk, 0, stream>>>(proj_w, prjt, 384, 384, 147456);
    wt_kernel<<<dim3((147456 + 255) / 256), blk, 0, stream>>>(mlp_w1, m1t, 384, 384, 147456);
    wt_kernel<<<dim3((147456 + 255) / 256), blk, 0, stream>>>(mlp_w2, m2t, 384, 384, 147456);

    for (int b0 = 0; b0 < 16; b0 += nb){
        const long Mc = (long)nb * T;
        const int  gy128 = (int)(Mc / 128);
        const int  gy64  = (int)(Mc / 64);
        const float* i1 = in1 + (long)b0 * T * 384;
        const float* i2 = in2 + (long)b0 * T * 384;
        float* outc = out + (long)b0 * T * 384;

        p = chunkBase;
        u16*  a0    = (u16*)alloc(Mc * 768 * 2);   // concat bf16 ; later: mlp hidden h
        u16*  h1b   = (u16*)alloc(Mc * 384 * 2);   // h1 bf16 ; later: t_att bf16
        u16*  xnb   = (u16*)alloc(Mc * 384 * 2);   // xn bf16 ; later: z bf16
        u16*  qpb   = (u16*)alloc(Mc * 192 * 2);   // qp bf16 (must be followed by allocs: OOB-read pad)
        float* xf   = (float*)alloc(Mc * 384 * 4); // x f32
        float* xnf  = (float*)alloc(Mc * 384 * 4); // xn f32
        float* kscr = (float*)alloc(Mc * 384 * 4); // k then q (f32)
        float* vf   = (float*)alloc(Mc * 384 * 4); // v f32
        float* kp   = (float*)alloc(Mc * 192 * 4); // kp f32
        float* xdv  = (float*)alloc(Mc * 4);
        float* Dn   = (float*)alloc(Mc * 4);
        float* kpsum= (float*)alloc((long)nb * 192 * 4 + (long)nb * 73728 * 4); // kpsum|kptv contiguous
        float* kptv = kpsum + (long)nb * 192;
        u16*  kptvb = (u16*)alloc((long)nb * 73728 * 2);
        (void)alloc(64L * 192 * 4);                 // tail pad

        // 0) a0 = bf16(concat)
        {
            long nq = Mc * 192;
            ca_kernel<<<dim3((unsigned)((nq + 255) / 256)), blk, 0, stream>>>(i1, i2, a0, nq);
        }
        // 1) h1 = GELU(a0 @ W1t^T + b1)  [bf16]
        gemm_bf16<1,0><<<dim3(3, gy128, 1), blk, 0, stream>>>(
            a0, 768, w1t, 768, h1b, 384, b1, nullptr, nullptr, (int)Mc, 768, 0,0,0,0);
        // 2) x = h1 @ W2t^T + b2  [f32]
        gemm_bf16<2,0><<<dim3(3, gy128, 1), blk, 0, stream>>>(
            h1b, 384, w2t, 384, xf, 384, b2, nullptr, nullptr, (int)Mc, 384, 0,0,0,0);
        // 3) LN1 -> xn (f32 + bf16)
        ln_kernel<<<dim3((unsigned)(Mc / 4)), blk, 0, stream>>>(xf, xnf, xnb, ln1_g, ln1_b);
        // 4) k = xn @ kqv_w[:, :384] (f32 SIMT)
        gemm_f32<0,0,0,0><<<dim3(6, gy64, 1), blk, 0, stream>>>(
            xnf, 384, kqv_w, 1152, kscr, 384, kqv_b, nullptr,
            (int)Mc, 384, 384, 1, 0,0,0,0, 0.f);
        xd_kernel<<<dim3((unsigned)(Mc / 4)), blk, 0, stream>>>(kscr, xdv);
        gemm_f32<0,1,2,0><<<dim3(3, gy64, 1), blk, 0, stream>>>(
            kscr, 384, w_prm, 384, kp, 192, nullptr, xdv,
            (int)Mc, 192, 384, 1, 0,0,0,0, prm_scale);
        // 5) q ; xd_q ; qp (bf16 out)
        gemm_f32<0,0,0,0><<<dim3(6, gy64, 1), blk, 0, stream>>>(
            xnf, 384, kqv_w + 384, 1152, kscr, 384, kqv_b + 384, nullptr,
            (int)Mc, 384, 384, 1, 0,0,0,0, 0.f);
        xd_kernel<<<dim3((unsigned)(Mc / 4)), blk, 0, stream>>>(kscr, xdv);
        gemm_f32<0,1,2,1><<<dim3(3, gy64, 1), blk, 0, stream>>>(
            kscr, 384, w_prm, 384, (float*)qpb, 192, nullptr, xdv,
            (int)Mc, 192, 384, 1, 0,0,0,0, prm_scale);
        // 6) v = xn_bf @ kqvt[768:] + b  [f32]
        gemm_bf16<2,0><<<dim3(3, gy128, 1), blk, 0, stream>>>(
            xnb, 384, kqvt + 768L * 384, 384, vf, 384, kqv_b + 768, nullptr, nullptr,
            (int)Mc, 384, 0,0,0,0);
        // 7) kpsum + kptv
        zero_kernel<<<dim3(512), blk, 0, stream>>>(kpsum, (long)nb * 192 + (long)nb * 73728);
        kpsum_kernel<<<dim3(nb, 7, 1), dim3(192), 0, stream>>>(kp, kpsum);
        gemm_f32<2,0,5,0><<<dim3(3, 6, nb * 7), blk, 0, stream>>>(
            vf, 384, kp, 192, kptv, 192, nullptr, nullptr,
            384, 192, 3136, 7, T*384, T*192, 73728, 0, 0.f);
        cvt_kernel<<<dim3((unsigned)(((long)nb * 73728 / 4 + 255) / 256)), blk, 0, stream>>>(
            kptv, kptvb, (long)nb * 73728 / 4);
        // 8) Dn
        dn_kernel<<<dim3((unsigned)(Mc / 4)), blk, 0, stream>>>(qpb, kpsum, Dn, (int)T);
        // 9) t_att = (qp @ kptv^T) / (Dn+1e-8)  [bf16, per-batch, guarded M]
        gemm_bf16<3,1><<<dim3(3, 25, nb), blk, 0, stream>>>(
            qpb, 192, kptvb, 192, h1b, 384, nullptr, Dn, nullptr,
            (int)T, 192, T*192, 73728, T*384, T);
        // 10) y = t_att @ proj + proj_b + v  -> outc (f32)
        gemm_bf16<4,0><<<dim3(3, gy128, 1), blk, 0, stream>>>(
            h1b, 384, prjt, 384, outc, 384, proj_b, nullptr, vf,
            (int)Mc, 384, 0,0,0,0);
        // 11) LN2 -> z bf16
        ln_kernel<<<dim3((unsigned)(Mc / 4)), blk, 0, stream>>>(outc, nullptr, xnb, ln2_g, ln2_b);
        // 12) h = GELU(z @ mlp1 + b)  [bf16] -> a0 region
        gemm_bf16<1,0><<<dim3(3, gy128, 1), blk, 0, stream>>>(
            xnb, 384, m1t, 384, a0, 384, mlp_b1, nullptr, nullptr,
            (int)Mc, 384, 0,0,0,0);
        // 13) out = h @ mlp2 + b + y  (in-place residual on outc)
        gemm_bf16<4,0><<<dim3(3, gy128, 1), blk, 0, stream>>>(
            a0, 384, m2t, 384, outc, 384, mlp_b2, nullptr, outc,
            (int)Mc, 384, 0,0,0,0);
    }
}

// Round 4
// 959.475 us; speedup vs baseline: 2.6517x; 1.5757x over previous
//
#include <hip/hip_runtime.h>
#include <math.h>

typedef unsigned short u16;
typedef unsigned int   u32;
typedef __attribute__((ext_vector_type(8))) short short8;
typedef __attribute__((ext_vector_type(4))) float f32x4;
typedef __attribute__((ext_vector_type(4))) u32   u32x4;

__device__ __forceinline__ float gelu_f(float x){
    return 0.5f * x * (1.0f + erff(x * 0.70710678118654752f));
}
__device__ __forceinline__ u16 f2b(float x){
    union{float f; u32 u;} v; v.f = x;
    u32 r = (v.u + 0x7fffu + ((v.u >> 16) & 1u)) >> 16;
    return (u16)r;
}
__device__ __forceinline__ float b2f(u16 h){
    union{u32 u; float f;} v; v.u = ((u32)h) << 16; return v.f;
}

// ===================== bf16 MFMA GEMM =====================
// A: bf16 [M][lda] row-major (k contiguous). B: bf16 [N][ldb] row-major (k contiguous).
// Tile 128x128, BK=32, 256 threads = 4 waves, each wave 64x64 (4x4 frags of 16x16).
// EPI: 0:+bias->bf16  1:+bias,GELU->bf16  2:+bias->f32  3:/(rowv[r]+1e-8)->bf16
//      4:+bias+resid->f32  5:exp(acc-rowv[r])*scale->f32  6:exp(acc-rowv[r])*scale->bf16
template<int EPI, int GUARD, int CGUARD>
__global__ __launch_bounds__(256)
void gemm_bf16(const u16* __restrict__ A, int lda,
               const u16* __restrict__ B, int ldb,
               void* __restrict__ Cv, int ldc,
               const float* __restrict__ bias,
               const float* __restrict__ rowv,
               const float* __restrict__ resid,
               int Mrows, int Ncols, int K,
               long sA, long sB, long sC, long sRV,
               float scale)
{
    const int bz = blockIdx.z;
    A += bz * sA;  B += bz * sB;
    const float* rv = (EPI == 3 || EPI == 5 || EPI == 6) ? rowv + bz * sRV : nullptr;

    __shared__ u16 As[4096];   // [kb][m][8]
    __shared__ u16 Bs[4096];   // [kb][n][8]

    const int tid = threadIdx.x;
    const int row0 = blockIdx.y * 128, col0 = blockIdx.x * 128;

    f32x4 acc[4][4] = {};

    const int l  = tid & 63, w = tid >> 6;
    const int wr = w >> 1,  wc = w & 1;
    const int g  = l >> 4,  mr = l & 15;

    const int cm = tid >> 1;          // row/col within tile
    const int ck = (tid & 1) * 2;     // kb base (0 or 2)

    for (int k0 = 0; k0 < K; k0 += 32){
        const u16* ga = A + (long)(row0 + cm) * lda + k0 + ck * 8;
        const u16* gb = B + (long)(col0 + cm) * ldb + k0 + ck * 8;
        u32x4 ra0 = *(const u32x4*)ga;
        u32x4 ra1 = *(const u32x4*)(ga + 8);
        u32x4 rb0 = *(const u32x4*)gb;
        u32x4 rb1 = *(const u32x4*)(gb + 8);
        __syncthreads();
        *(u32x4*)&As[((ck + 0) * 128 + cm) * 8] = ra0;
        *(u32x4*)&As[((ck + 1) * 128 + cm) * 8] = ra1;
        *(u32x4*)&Bs[((ck + 0) * 128 + cm) * 8] = rb0;
        *(u32x4*)&Bs[((ck + 1) * 128 + cm) * 8] = rb1;
        __syncthreads();

        short8 af[4], bfr[4];
        #pragma unroll
        for (int i = 0; i < 4; i++)
            af[i] = *(const short8*)&As[(g * 128 + wr * 64 + i * 16 + mr) * 8];
        #pragma unroll
        for (int j = 0; j < 4; j++)
            bfr[j] = *(const short8*)&Bs[(g * 128 + wc * 64 + j * 16 + mr) * 8];
        #pragma unroll
        for (int i = 0; i < 4; i++)
            #pragma unroll
            for (int j = 0; j < 4; j++)
                acc[i][j] = __builtin_amdgcn_mfma_f32_16x16x32_bf16(af[i], bfr[j], acc[i][j], 0, 0, 0);
    }

    float* Cf = (float*)Cv + bz * sC;
    u16*   Cb = (u16*)Cv   + bz * sC;

    #pragma unroll
    for (int i = 0; i < 4; i++){
        #pragma unroll
        for (int j = 0; j < 4; j++){
            const int col = col0 + wc * 64 + j * 16 + mr;
            if (CGUARD && col >= Ncols) continue;
            float bv = 0.f;
            if (EPI == 0 || EPI == 1 || EPI == 2 || EPI == 4) bv = bias[col];
            #pragma unroll
            for (int r = 0; r < 4; r++){
                const int row = row0 + wr * 64 + i * 16 + g * 4 + r;
                if (GUARD && row >= Mrows) continue;
                float vv = acc[i][j][r];
                if      (EPI == 1){ vv += bv; vv = gelu_f(vv); }
                else if (EPI == 3){ vv = vv / (rv[row] + 1e-8f); }
                else if (EPI == 4){ vv += bv + resid[(long)row * ldc + col]; }
                else if (EPI == 5 || EPI == 6){ vv = expf(vv - rv[row]) * scale; }
                else              { vv += bv; }
                if (EPI == 2 || EPI == 4 || EPI == 5) Cf[(long)row * ldc + col] = vv;
                else                                   Cb[(long)row * ldc + col] = f2b(vv);
            }
        }
    }
}

// ===================== fp32 SIMT GEMM (kptv only) =====================
// AMODE2: A transposed A[k*lda+r]; BMODE0: B row-major; EPI5: atomicAdd into C
__global__ __launch_bounds__(256)
void gemm_f32_kptv(const float* __restrict__ A, int lda,
                   const float* __restrict__ Bp, int ldb,
                   float* __restrict__ C, int ldc,
                   int K, int splitK,
                   long sA, long sB, long sC)
{
    const int bz = blockIdx.z;
    const int b  = bz / splitK, kc = bz % splitK;
    A += (long)b * sA;
    Bp += (long)b * sB;
    C  += (long)b * sC;

    __shared__ float As[16][64];
    __shared__ float Bs[16][64];
    const int tid = threadIdx.x;
    const int tx = tid & 15, ty = tid >> 4;
    const int row0 = blockIdx.y * 64, col0 = blockIdx.x * 64;

    float acc[4][4] = {};

    const int kLen = K / splitK;
    const int kB = kc * kLen, kE = kB + kLen;

    for (int k0 = kB; k0 < kE; k0 += 16){
        {
            const int dl = tid & 63, tl = tid >> 6;
            #pragma unroll
            for (int i = 0; i < 4; i++){
                const int t = k0 + tl + i*4;
                As[tl + i*4][dl] = A[(long)t * lda + row0 + dl];
            }
        }
        {
            const int kk = tid >> 4, ng = (tid & 15) * 4;
            *(float4*)&Bs[kk][ng] =
                *(const float4*)&Bp[(long)(k0 + kk) * ldb + col0 + ng];
        }
        __syncthreads();
        #pragma unroll
        for (int kk = 0; kk < 16; kk++){
            float4 a4 = *(const float4*)&As[kk][ty*4];
            float4 b4 = *(const float4*)&Bs[kk][tx*4];
            float a[4]  = {a4.x, a4.y, a4.z, a4.w};
            float bb[4] = {b4.x, b4.y, b4.z, b4.w};
            #pragma unroll
            for (int i = 0; i < 4; i++)
                #pragma unroll
                for (int j = 0; j < 4; j++)
                    acc[i][j] = fmaf(a[i], bb[j], acc[i][j]);
        }
        __syncthreads();
    }

    #pragma unroll
    for (int i = 0; i < 4; i++){
        const int r = row0 + ty*4 + i;
        #pragma unroll
        for (int j = 0; j < 4; j++)
            atomicAdd(&C[(long)r * ldc + col0 + tx*4 + j], acc[i][j]);
    }
}

// LayerNorm over D=384 (f32 in); optional f32 and bf16 outputs.
__global__ __launch_bounds__(256)
void ln_kernel(const float* __restrict__ x, float* __restrict__ of, u16* __restrict__ ob,
               const float* __restrict__ g, const float* __restrict__ bta)
{
    const int lane = threadIdx.x & 63;
    const long r = (long)blockIdx.x * 4 + (threadIdx.x >> 6);
    const float* xr = x + r * 384;
    float v[6]; float s = 0.f;
    #pragma unroll
    for (int i = 0; i < 6; i++){ v[i] = xr[lane + i*64]; s += v[i]; }
    #pragma unroll
    for (int off = 32; off; off >>= 1) s += __shfl_xor(s, off);
    const float mu = s * (1.0f/384.0f);
    float q = 0.f;
    #pragma unroll
    for (int i = 0; i < 6; i++){ float d = v[i] - mu; q += d*d; }
    #pragma unroll
    for (int off = 32; off; off >>= 1) q += __shfl_xor(q, off);
    const float inv = rsqrtf(q * (1.0f/384.0f) + 1e-5f);
    #pragma unroll
    for (int i = 0; i < 6; i++){
        const int c = lane + i*64;
        const float val = (v[i] - mu) * inv * g[c] + bta[c];
        if (of) of[r * 384 + c] = val;
        if (ob) ob[r * 384 + c] = f2b(val);
    }
}

// xd[r] = 0.5*||x_row||^2 over 384 bf16 cols
__global__ __launch_bounds__(256)
void xd_b_kernel(const u16* __restrict__ x, float* __restrict__ xd)
{
    const int lane = threadIdx.x & 63;
    const long r = (long)blockIdx.x * 4 + (threadIdx.x >> 6);
    const u16* xr = x + r * 384;
    float s = 0.f;
    #pragma unroll
    for (int i = 0; i < 6; i++){ float a = b2f(xr[lane + i*64]); s += a*a; }
    #pragma unroll
    for (int off = 32; off; off >>= 1) s += __shfl_xor(s, off);
    if (lane == 0) xd[r] = 0.5f * s;
}

// Dn[r] = dot(qp_bf16[r,:192], kpsum[r/T,:192])
__global__ __launch_bounds__(256)
void dn_kernel(const u16* __restrict__ qp, const float* __restrict__ kpsum,
               float* __restrict__ Dn, int T)
{
    const int lane = threadIdx.x & 63;
    const long r = (long)blockIdx.x * 4 + (threadIdx.x >> 6);
    const int b = (int)(r / T);
    const u16* qr = qp + r * 192;
    const float* ks = kpsum + (long)b * 192;
    float s = 0.f;
    #pragma unroll
    for (int i = 0; i < 3; i++){ const int m = lane + i*64; s += b2f(qr[m]) * ks[m]; }
    #pragma unroll
    for (int off = 32; off; off >>= 1) s += __shfl_xor(s, off);
    if (lane == 0) Dn[r] = s;
}

__global__ __launch_bounds__(192)
void kpsum_kernel(const float* __restrict__ kp, float* __restrict__ kpsum)
{
    const int b = blockIdx.x, ch = blockIdx.y, m = threadIdx.x;
    const float* base = kp + ((long)b * 3136 + (long)ch * 448) * 192 + m;
    float s = 0.f;
    for (int t = 0; t < 448; t++) s += base[(long)t * 192];
    atomicAdd(&kpsum[b * 192 + m], s);
}

__global__ __launch_bounds__(256)
void zero_kernel(float* __restrict__ p, long n)
{
    long i = (long)blockIdx.x * 256 + threadIdx.x;
    long stride = (long)gridDim.x * 256;
    for (; i < n; i += stride) p[i] = 0.f;
}

// concat(in1,in2) row-major -> bf16 [Mc][768]
__global__ __launch_bounds__(256)
void ca_kernel(const float* __restrict__ i1, const float* __restrict__ i2,
               u16* __restrict__ a0, long nquad)
{
    long idx = (long)blockIdx.x * 256 + threadIdx.x;
    if (idx >= nquad) return;
    const long r = idx / 192;
    const int  c0 = (int)(idx % 192) * 4;
    const float* src = (c0 < 384) ? &i1[r * 384 + c0] : &i2[r * 384 + (c0 - 384)];
    float4 v = *(const float4*)src;
    u32 w0 = (u32)f2b(v.x) | ((u32)f2b(v.y) << 16);
    u32 w1 = (u32)f2b(v.z) | ((u32)f2b(v.w) << 16);
    *(uint2*)&a0[r * 768 + c0] = make_uint2(w0, w1);
}

// wt[n*K + k] = bf16(w[k*N + n])
__global__ __launch_bounds__(256)
void wt_kernel(const float* __restrict__ w, u16* __restrict__ wt, int K, int N, long total)
{
    long idx = (long)blockIdx.x * 256 + threadIdx.x;
    if (idx >= total) return;
    const long n = idx / K, k = idx - n * K;
    wt[idx] = f2b(w[k * N + n]);
}

// flat f32 -> bf16
__global__ __launch_bounds__(256)
void cvt_kernel(const float* __restrict__ s, u16* __restrict__ d, long n4)
{
    long idx = (long)blockIdx.x * 256 + threadIdx.x;
    if (idx >= n4) return;
    float4 v = *(const float4*)&s[idx * 4];
    u32 w0 = (u32)f2b(v.x) | ((u32)f2b(v.y) << 16);
    u32 w1 = (u32)f2b(v.z) | ((u32)f2b(v.w) << 16);
    *(uint2*)&d[idx * 4] = make_uint2(w0, w1);
}

extern "C" void kernel_launch(void* const* d_in, const int* in_sizes, int n_in,
                              void* d_out, int out_size, void* d_ws, size_t ws_size,
                              hipStream_t stream)
{
    const long T = 3136;
    const float prm_scale = 0.07216878364870322f;  // 1/sqrt(192)

    const float* in1    = (const float*)d_in[0];
    const float* in2    = (const float*)d_in[1];
    const float* W1     = (const float*)d_in[2];
    const float* b1     = (const float*)d_in[3];
    const float* W2     = (const float*)d_in[4];
    const float* b2     = (const float*)d_in[5];
    const float* kqv_w  = (const float*)d_in[6];
    const float* kqv_b  = (const float*)d_in[7];
    const float* proj_w = (const float*)d_in[8];
    const float* proj_b = (const float*)d_in[9];
    const float* ln1_g  = (const float*)d_in[10];
    const float* ln1_b  = (const float*)d_in[11];
    const float* ln2_g  = (const float*)d_in[12];
    const float* ln2_b  = (const float*)d_in[13];
    const float* mlp_w1 = (const float*)d_in[14];
    const float* mlp_b1 = (const float*)d_in[15];
    const float* mlp_w2 = (const float*)d_in[16];
    const float* mlp_b2 = (const float*)d_in[17];
    const float* w_prm  = (const float*)d_in[18];
    float* out = (float*)d_out;

    // ---- workspace layout ----
    char* p = (char*)d_ws;
    auto alloc = [&](long bytes)->char*{ char* r = p; p += (bytes + 255) & ~255L; return r; };

    // chunk-invariant: bf16 weights
    u16* w1t   = (u16*)alloc(294912L * 2);   // [384][768]
    u16* w2t   = (u16*)alloc(147456L * 2);   // [384][384]
    u16* kqvt  = (u16*)alloc(442368L * 2);   // [1152][384]
    u16* prjt  = (u16*)alloc(147456L * 2);
    u16* m1t   = (u16*)alloc(147456L * 2);
    u16* m2t   = (u16*)alloc(147456L * 2);
    u16* wprmb = (u16*)alloc(256L * 384 * 2); // [256 pad][384], rows 192+ zeroed
    char* chunkBase = p;

    // per-batch ws bytes:
    // bf16: a0 768 + h1b 384 + xnb 384 + qpb 192 + kb 384 + qb 384 = 2496*T*2
    // f32 : xf 384 + vf 384 + kp 192 + xd 1 + Dn 1 = 962*T*4
    // f32 : kpsum 192 + kptv 73728 ; bf16: kptvb 73728
    const long perBatch = 2496L * T * 2 + 962L * T * 4 + (192L + 73728L) * 4 + 73728L * 2;
    const long fixed = (long)(chunkBase - (char*)d_ws) + (1L << 20);
    int nb = 2;
    for (int cand = 16; cand >= 2; cand >>= 1){
        if (fixed + (long)cand * perBatch + 64L * 1024 <= (long)ws_size){ nb = cand; break; }
    }

    const dim3 blk(256);

    // weight transpose/convert (idempotent per call)
    wt_kernel<<<dim3((294912 + 255) / 256), blk, 0, stream>>>(W1, w1t, 768, 384, 294912);
    wt_kernel<<<dim3((147456 + 255) / 256), blk, 0, stream>>>(W2, w2t, 384, 384, 147456);
    wt_kernel<<<dim3((442368 + 255) / 256), blk, 0, stream>>>(kqv_w, kqvt, 384, 1152, 442368);
    wt_kernel<<<dim3((147456 + 255) / 256), blk, 0, stream>>>(proj_w, prjt, 384, 384, 147456);
    wt_kernel<<<dim3((147456 + 255) / 256), blk, 0, stream>>>(mlp_w1, m1t, 384, 384, 147456);
    wt_kernel<<<dim3((147456 + 255) / 256), blk, 0, stream>>>(mlp_w2, m2t, 384, 384, 147456);
    zero_kernel<<<dim3(64), blk, 0, stream>>>((float*)wprmb, 256L * 384 / 2);
    cvt_kernel<<<dim3((18432 + 255) / 256), blk, 0, stream>>>(w_prm, wprmb, 18432);

    for (int b0 = 0; b0 < 16; b0 += nb){
        const long Mc = (long)nb * T;
        const int  gy128 = (int)(Mc / 128);
        const float* i1 = in1 + (long)b0 * T * 384;
        const float* i2 = in2 + (long)b0 * T * 384;
        float* outc = out + (long)b0 * T * 384;

        p = chunkBase;
        u16*  a0    = (u16*)alloc(Mc * 768 * 2);   // concat bf16 ; later: mlp hidden h
        u16*  h1b   = (u16*)alloc(Mc * 384 * 2);   // h1 bf16 ; later: t_att bf16
        u16*  xnb   = (u16*)alloc(Mc * 384 * 2);   // xn bf16 ; later: z bf16
        u16*  qpb   = (u16*)alloc(Mc * 192 * 2);   // qp bf16 (followed by allocs: OOB-read pad)
        u16*  kb    = (u16*)alloc(Mc * 384 * 2);   // k bf16
        u16*  qb    = (u16*)alloc(Mc * 384 * 2);   // q bf16
        float* xf   = (float*)alloc(Mc * 384 * 4); // x f32
        float* vf   = (float*)alloc(Mc * 384 * 4); // v f32
        float* kp   = (float*)alloc(Mc * 192 * 4); // kp f32
        float* xdv  = (float*)alloc(Mc * 4);
        float* Dn   = (float*)alloc(Mc * 4);
        float* kpsum= (float*)alloc((long)nb * 192 * 4 + (long)nb * 73728 * 4);
        float* kptv = kpsum + (long)nb * 192;
        u16*  kptvb = (u16*)alloc((long)nb * 73728 * 2);
        (void)alloc(64L * 1024);                    // tail pad

        // 0) a0 = bf16(concat)
        {
            long nq = Mc * 192;
            ca_kernel<<<dim3((unsigned)((nq + 255) / 256)), blk, 0, stream>>>(i1, i2, a0, nq);
        }
        // 1) h1 = GELU(a0 @ W1t^T + b1)  [bf16]
        gemm_bf16<1,0,0><<<dim3(3, gy128, 1), blk, 0, stream>>>(
            a0, 768, w1t, 768, h1b, 384, b1, nullptr, nullptr, (int)Mc, 384, 768, 0,0,0,0, 0.f);
        // 2) x = h1 @ W2t^T + b2  [f32]
        gemm_bf16<2,0,0><<<dim3(3, gy128, 1), blk, 0, stream>>>(
            h1b, 384, w2t, 384, xf, 384, b2, nullptr, nullptr, (int)Mc, 384, 384, 0,0,0,0, 0.f);
        // 3) LN1 -> xn bf16
        ln_kernel<<<dim3((unsigned)(Mc / 4)), blk, 0, stream>>>(xf, nullptr, xnb, ln1_g, ln1_b);
        // 4) k = xn @ kqvt[0:384] + b  [bf16]
        gemm_bf16<0,0,0><<<dim3(3, gy128, 1), blk, 0, stream>>>(
            xnb, 384, kqvt, 384, kb, 384, kqv_b, nullptr, nullptr, (int)Mc, 384, 384, 0,0,0,0, 0.f);
        xd_b_kernel<<<dim3((unsigned)(Mc / 4)), blk, 0, stream>>>(kb, xdv);
        // 5) kp = exp(k @ wprm^T - xd)*scale  [f32, N=192 col-guarded]
        gemm_bf16<5,0,1><<<dim3(2, gy128, 1), blk, 0, stream>>>(
            kb, 384, wprmb, 384, kp, 192, nullptr, xdv, nullptr, (int)Mc, 192, 384, 0,0,0,0, prm_scale);
        // 6) q ; xd_q ; qp [bf16]
        gemm_bf16<0,0,0><<<dim3(3, gy128, 1), blk, 0, stream>>>(
            xnb, 384, kqvt + 384L * 384, 384, qb, 384, kqv_b + 384, nullptr, nullptr, (int)Mc, 384, 384, 0,0,0,0, 0.f);
        xd_b_kernel<<<dim3((unsigned)(Mc / 4)), blk, 0, stream>>>(qb, xdv);
        gemm_bf16<6,0,1><<<dim3(2, gy128, 1), blk, 0, stream>>>(
            qb, 384, wprmb, 384, qpb, 192, nullptr, xdv, nullptr, (int)Mc, 192, 384, 0,0,0,0, prm_scale);
        // 7) v = xn @ kqvt[768:] + b  [f32]
        gemm_bf16<2,0,0><<<dim3(3, gy128, 1), blk, 0, stream>>>(
            xnb, 384, kqvt + 768L * 384, 384, vf, 384, kqv_b + 768, nullptr, nullptr, (int)Mc, 384, 384, 0,0,0,0, 0.f);
        // 8) kpsum + kptv
        zero_kernel<<<dim3(512), blk, 0, stream>>>(kpsum, (long)nb * 192 + (long)nb * 73728);
        kpsum_kernel<<<dim3(nb, 7, 1), dim3(192), 0, stream>>>(kp, kpsum);
        gemm_f32_kptv<<<dim3(3, 6, nb * 7), blk, 0, stream>>>(
            vf, 384, kp, 192, kptv, 192, 3136, 7, T*384, T*192, 73728);
        cvt_kernel<<<dim3((unsigned)(((long)nb * 73728 / 4 + 255) / 256)), blk, 0, stream>>>(
            kptv, kptvb, (long)nb * 73728 / 4);
        // 9) Dn
        dn_kernel<<<dim3((unsigned)(Mc / 4)), blk, 0, stream>>>(qpb, kpsum, Dn, (int)T);
        // 10) t_att = (qp @ kptv^T) / (Dn+1e-8)  [bf16, per-batch, row-guarded]
        gemm_bf16<3,1,0><<<dim3(3, 25, nb), blk, 0, stream>>>(
            qpb, 192, kptvb, 192, h1b, 384, nullptr, Dn, nullptr,
            (int)T, 384, 192, T*192, 73728, T*384, T, 0.f);
        // 11) y = t_att @ proj + proj_b + v  -> outc (f32)
        gemm_bf16<4,0,0><<<dim3(3, gy128, 1), blk, 0, stream>>>(
            h1b, 384, prjt, 384, outc, 384, proj_b, nullptr, vf, (int)Mc, 384, 384, 0,0,0,0, 0.f);
        // 12) LN2 -> z bf16
        ln_kernel<<<dim3((unsigned)(Mc / 4)), blk, 0, stream>>>(outc, nullptr, xnb, ln2_g, ln2_b);
        // 13) h = GELU(z @ mlp1 + b)  [bf16] -> a0 region
        gemm_bf16<1,0,0><<<dim3(3, gy128, 1), blk, 0, stream>>>(
            xnb, 384, m1t, 384, a0, 384, mlp_b1, nullptr, nullptr, (int)Mc, 384, 384, 0,0,0,0, 0.f);
        // 14) out = h @ mlp2 + b + y  (in-place residual on outc)
        gemm_bf16<4,0,0><<<dim3(3, gy128, 1), blk, 0, stream>>>(
            a0, 384, m2t, 384, outc, 384, mlp_b2, nullptr, outc, (int)Mc, 384, 384, 0,0,0,0, 0.f);
    }
}